// Round 27
// baseline (78.931 us; speedup 1.0000x reference)
//
#include <hip/hip_runtime.h>

// Problem constants: B=32, L=2, F=65536, D=768
#define BB 32
#define LL 2
#define FF 65536
#define DD 768
#define F4 (FF / 4)        // 16384 float4 per f row
#define LD (LL * DD)       // 1536
#define BL (BB * LD)       // 49152 outputs

#define NSTEPS (FF / 16)   // 4096 K16-steps
#define NF 128             // F-chunks; grid (NF, 2) = 256 blocks = 1/CU
#define KS (NSTEPS / NF)   // 32 K16-steps per chunk

// bf16-packed partials: per (c,l) chunk, 24 uint slots x 512 threads.
#define PCHUNK 12288                        // uints per (c,l) chunk (24*512)
#define PART_BYTES ((size_t)NF * 2 * PCHUNK * 4)   // 12.58 MB

typedef __attribute__((ext_vector_type(8)))  short short8;   // 8 bf16 (4 VGPR)
typedef __attribute__((ext_vector_type(16))) float float16;  // 16 fp32 acc

// fp32 -> bf16 round-to-nearest-even (finite inputs)
static __device__ __forceinline__ unsigned bf16rne(float x)
{
    unsigned u = __float_as_uint(x);
    return (u + 0x7fffu + ((u >> 16) & 1u)) >> 16;
}

// Stage 1: MFMA partial GEMM, linear weight streaming, triple-buffered LDS,
// counted vmcnt (R24/R25 structure). Single change vs R26: weight
// global_load_lds aux 2 -> 18 = NT|SC1 (CPol: SC0=bit0, NT=bit1, SC1=bit4).
// NT alone still ALLOCATES in L2 (evict-first); SC1 raises scope so the
// single-use 402 MB stream skips XCD-L2 allocation entirely (HBM/L3 -> LDS).
// Read-only data: any cache scope returns identical bytes (hint-only).
// grid = (NF, 2); block = 512 (8 waves). Block tile: M=32 x N=768.
// A-frag (verified): row = lane&31, k = s*16 + (lane>>5)*8 + j.
// C/D (verified): col = lane&31, row b = (r&3) + 8*(r>>2) + 4*(lane>>5).
// LDS 144 KB -> 1 block/CU; VGPR ~115 under (512,2) cap 256 (spill-safe).
__global__ __launch_bounds__(512, 2) void cc_mfma(
    const float4* __restrict__ f4,     // [32][16384]
    const float* __restrict__ weight,  // [2][65536][768]
    unsigned* __restrict__ partials)   // [NF*2][PCHUNK] bf16-packed
{
    __shared__ float lbuf[3][16 * DD]; // 3 x 48 KB = 144 KB

    const int tid  = threadIdx.x;
    const int lane = tid & 63;
    const int wv   = tid >> 6;         // 0..7
    const int c    = blockIdx.x;       // 0..NF-1
    const int l    = blockIdx.y;       // 0..1
    const int col  = lane & 31;
    const int half = lane >> 5;

    const float4* __restrict__ wchunk =
        (const float4*)(weight + ((size_t)l * FF + (size_t)c * (KS * 16)) * DD);
    // lane's f stream: row b = col, float4 index c*KS*4 + s*4 + half*2
    const float4* __restrict__ fbase =
        f4 + (size_t)col * F4 + (size_t)c * KS * 4 + half * 2;

    float16 acc[3];
#pragma unroll
    for (int i = 0; i < 3; ++i)
#pragma unroll
        for (int r = 0; r < 16; ++r) acc[i][r] = 0.f;

#define FENCE() asm volatile("" ::: "memory")

#define ISSUE_STAGE(BIDX, SIDX)                                               \
    do {                                                                      \
        const float4* gsrc_ = wchunk + (size_t)(SIDX) * 3072;                 \
        float4* nb4_ = (float4*)lbuf[(BIDX)];                                 \
        _Pragma("unroll")                                                     \
        for (int t_ = 0; t_ < 6; ++t_) {                                      \
            int idx_ = t_ * 512 + tid;                                        \
            __builtin_amdgcn_global_load_lds(                                 \
                (const __attribute__((address_space(1))) void*)(gsrc_ + idx_),\
                (__attribute__((address_space(3))) void*)(nb4_ + idx_),       \
                16, 0, 18 /* NT|SC1: stream past L2, no allocation */);       \
        }                                                                     \
    } while (0)

#define COMPUTE(BIDX, FX0, FX1)                                               \
    do {                                                                      \
        short8 a8_;                                                           \
        a8_[0] = (short)bf16rne((FX0).x);                                     \
        a8_[1] = (short)bf16rne((FX0).y);                                     \
        a8_[2] = (short)bf16rne((FX0).z);                                     \
        a8_[3] = (short)bf16rne((FX0).w);                                     \
        a8_[4] = (short)bf16rne((FX1).x);                                     \
        a8_[5] = (short)bf16rne((FX1).y);                                     \
        a8_[6] = (short)bf16rne((FX1).z);                                     \
        a8_[7] = (short)bf16rne((FX1).w);                                     \
        const float* lb_ = lbuf[(BIDX)];                                      \
        const int rbase_ = half * 8;                                          \
        _Pragma("unroll")                                                     \
        for (int i_ = 0; i_ < 3; ++i_) {                                      \
            const int d_ = 96 * wv + 32 * i_ + col;                           \
            float w_[8];                                                      \
            _Pragma("unroll")                                                 \
            for (int j_ = 0; j_ < 8; ++j_)                                    \
                w_[j_] = lb_[(rbase_ + j_) * DD + d_];  /* 2 lanes/bank */    \
            short8 b8_;                                                       \
            _Pragma("unroll")                                                 \
            for (int j_ = 0; j_ < 8; ++j_)                                    \
                b8_[j_] = (short)bf16rne(w_[j_]);                             \
            acc[i_] = __builtin_amdgcn_mfma_f32_32x32x16_bf16(                \
                a8_, b8_, acc[i_], 0, 0, 0);                                  \
        }                                                                     \
    } while (0)

#define SUBITER(S, BIDX, FX0, FX1, NBIDX, NF0, NF1)                           \
    do {                                                                      \
        if ((S) == KS - 1) asm volatile("s_waitcnt vmcnt(0)" ::: "memory");   \
        else               asm volatile("s_waitcnt vmcnt(8)" ::: "memory");   \
        asm volatile("s_barrier" ::: "memory");                               \
        if ((S) + 2 < KS) {                                                   \
            ISSUE_STAGE(NBIDX, (S) + 2);                                      \
            NF0 = fbase[(size_t)((S) + 2) * 4];                               \
            NF1 = fbase[(size_t)((S) + 2) * 4 + 1];                           \
            FENCE();                                                          \
        }                                                                     \
        COMPUTE(BIDX, FX0, FX1);                                              \
    } while (0)

    float4 fA0, fA1, fB0, fB1, fC0, fC1;
    fC0 = make_float4(0.f, 0.f, 0.f, 0.f);
    fC1 = fC0;

    // prologue: groups 0 and 1 (group order pinned by fences)
    ISSUE_STAGE(0, 0);
    fA0 = fbase[0]; fA1 = fbase[1];
    FENCE();
    ISSUE_STAGE(1, 1);
    fB0 = fbase[4]; fB1 = fbase[5];
    FENCE();

    for (int st = 0; st < KS; st += 3) {
        SUBITER(st, 0, fA0, fA1, 2, fC0, fC1);
        if (st + 1 < KS) SUBITER(st + 1, 1, fB0, fB1, 0, fA0, fA1);
        if (st + 2 < KS) SUBITER(st + 2, 2, fC0, fC1, 1, fB0, fB1);
    }

    // epilogue: bf16-packed, lane-major (slot j = i*8+rp -> 2KB contiguous)
    unsigned* __restrict__ pp = partials + (size_t)(c * 2 + l) * PCHUNK;
#pragma unroll
    for (int i = 0; i < 3; ++i)
#pragma unroll
        for (int rp = 0; rp < 8; ++rp) {
            unsigned u = bf16rne(acc[i][2 * rp]) |
                         (bf16rne(acc[i][2 * rp + 1]) << 16);
            pp[(i * 8 + rp) * 512 + tid] = u;
        }
}

// Stage 2: unpack + reduce + bias. 24576 positions x 2 bf16 values each.
__global__ __launch_bounds__(256) void cc_stage2(
    const unsigned* __restrict__ partials,
    const float* __restrict__ bias,
    float* __restrict__ out)
{
    int t = blockIdx.x * 256 + threadIdx.x;   // 0 .. 24575
    if (t >= 2 * PCHUNK) return;
    int l   = t / PCHUNK;
    int rem = t - l * PCHUNK;
    int j   = rem >> 9;          // 0..23
    int tid = rem & 511;
    int wv = tid >> 6, lane = tid & 63, col = lane & 31, half = lane >> 5;
    int i = j >> 3, rp = j & 7;
    int r0 = 2 * rp, r1 = 2 * rp + 1;

    float s0 = 0.f, s1 = 0.f;
    const unsigned* __restrict__ p = partials + (size_t)l * PCHUNK + rem;
#pragma unroll 16
    for (int c = 0; c < NF; ++c, p += 2 * PCHUNK) {
        unsigned u = *p;
        s0 += __uint_as_float(u << 16);
        s1 += __uint_as_float(u & 0xffff0000u);
    }

    int d  = 96 * wv + 32 * i + col;
    int ld = l * DD + d;
    int b0 = (r0 & 3) + 8 * (r0 >> 2) + 4 * half;
    int b1 = (r1 & 3) + 8 * (r1 >> 2) + 4 * half;
    float bs = bias[ld];
    out[(size_t)b0 * LD + ld] = bs + s0;
    out[(size_t)b1 * LD + ld] = bs + s1;
}

// Correctness-only fallback if workspace is too small (fp32 path).
__global__ __launch_bounds__(256) void cc_direct(
    const float* __restrict__ f,
    const float* __restrict__ weight,
    const float* __restrict__ bias,
    float* __restrict__ out)
{
    int o = blockIdx.x * 256 + threadIdx.x;
    if (o >= BL) return;
    int b  = o / LD;
    int ld = o - b * LD;
    int l  = ld / DD;
    int d  = ld - l * DD;
    float s = bias[ld];
    const float* wp = weight + (size_t)l * FF * DD + d;
    const float* fp = f + (size_t)b * FF;
    for (int fi = 0; fi < FF; ++fi)
        s = fmaf(fp[fi], wp[(size_t)fi * DD], s);
    out[o] = s;
}

extern "C" void kernel_launch(void* const* d_in, const int* in_sizes, int n_in,
                              void* d_out, int out_size, void* d_ws, size_t ws_size,
                              hipStream_t stream)
{
    const float* f      = (const float*)d_in[0];   // 32 x 65536
    const float* weight = (const float*)d_in[1];   // 2 x 65536 x 768
    const float* bias   = (const float*)d_in[2];   // 2 x 768
    float* out          = (float*)d_out;           // 32 x 2 x 768

    if (ws_size < PART_BYTES) {
        cc_direct<<<(BL + 255) / 256, 256, 0, stream>>>(f, weight, bias, out);
        return;
    }

    unsigned* partials = (unsigned*)d_ws;

    dim3 grid1(NF, LL);
    cc_mfma<<<grid1, 512, 0, stream>>>((const float4*)f, weight, partials);

    cc_stage2<<<(2 * PCHUNK + 255) / 256, 256, 0, stream>>>(
        partials, bias, out);
}